// Round 3
// baseline (511.613 us; speedup 1.0000x reference)
//
#include <hip/hip_runtime.h>

#define N_SUM 2048
#define HIDD 128
#define NEDGE 16384
#define ROWS (N_SUM * 64)

typedef short short8 __attribute__((ext_vector_type(8)));
typedef float floatx4 __attribute__((ext_vector_type(4)));
typedef unsigned short ushort_t;

__device__ __forceinline__ ushort_t f2bf(float f) {
    unsigned u = __builtin_bit_cast(unsigned, f);
    u += 0x7fffu + ((u >> 16) & 1u);   // RNE
    return (ushort_t)(u >> 16);
}
__device__ __forceinline__ float bf2f(ushort_t h) {
    return __builtin_bit_cast(float, (unsigned)h << 16);
}
__device__ __forceinline__ void unpack8(uint4 v, float* f) {
    f[0] = bf2f(v.x & 0xffff); f[1] = bf2f(v.x >> 16);
    f[2] = bf2f(v.y & 0xffff); f[3] = bf2f(v.y >> 16);
    f[4] = bf2f(v.z & 0xffff); f[5] = bf2f(v.z >> 16);
    f[6] = bf2f(v.w & 0xffff); f[7] = bf2f(v.w >> 16);
}
__device__ __forceinline__ uint4 pack8(const float* f) {
    uint4 v;
    v.x = f2bf(f[0]) | ((unsigned)f2bf(f[1]) << 16);
    v.y = f2bf(f[2]) | ((unsigned)f2bf(f[3]) << 16);
    v.z = f2bf(f[4]) | ((unsigned)f2bf(f[5]) << 16);
    v.w = f2bf(f[6]) | ((unsigned)f2bf(f[7]) << 16);
    return v;
}

// ---------------- CSR build ----------------
__global__ __launch_bounds__(256) void zero_ints(int* p, int n) {
    int i = blockIdx.x * 256 + threadIdx.x;
    if (i < n) p[i] = 0;
}

__global__ __launch_bounds__(256) void count_deg(const int* __restrict__ dst, int* __restrict__ deg) {
    int e = blockIdx.x * 256 + threadIdx.x;
    if (e < NEDGE) atomicAdd(&deg[dst[e]], 1);
}

__global__ __launch_bounds__(256) void scan_deg(const int* __restrict__ deg, int* __restrict__ row_ptr) {
    __shared__ int csum[256];
    int t = threadIdx.x;
    int loc[8];
    int s = 0;
#pragma unroll
    for (int q = 0; q < 8; q++) { loc[q] = s; s += deg[t * 8 + q]; }
    csum[t] = s;
    __syncthreads();
    for (int off = 1; off < 256; off <<= 1) {
        int v = (t >= off) ? csum[t - off] : 0;
        __syncthreads();
        csum[t] += v;
        __syncthreads();
    }
    int base = (t == 0) ? 0 : csum[t - 1];
#pragma unroll
    for (int q = 0; q < 8; q++) row_ptr[t * 8 + q] = base + loc[q];
    if (t == 255) row_ptr[2048] = csum[255];
}

__global__ __launch_bounds__(256) void fill_csr(const int* __restrict__ src, const int* __restrict__ dst,
                                                const int* __restrict__ row_ptr, int* __restrict__ cursor,
                                                int* __restrict__ col) {
    int e = blockIdx.x * 256 + threadIdx.x;
    if (e < NEDGE) {
        int d = dst[e];
        int pos = atomicAdd(&cursor[d], 1);
        col[row_ptr[d] + pos] = src[e];
    }
}

// ---------------- weight prep ----------------
// w1t0: [128 n][32 k] bf16 (k>=16 zero) from W1_first
// w2lt: [64 n][128 k] bf16 from W2_last
// bvec[lm][c] = sum_o b2m[lm][o] * W1r[lm][o][c]   (lm = 0..2 -> fused layer lm+1)
__global__ __launch_bounds__(256) void prep_small(const float* __restrict__ W1f, const float* __restrict__ W2l,
                                                  const float* __restrict__ b2m, const float* __restrict__ W1r,
                                                  ushort_t* __restrict__ w1t0, ushort_t* __restrict__ w2lt,
                                                  float* __restrict__ bvec) {
    int idx = blockIdx.x * 256 + threadIdx.x;
    if (idx < 4096) {
        int nn = idx >> 5, k = idx & 31;
        w1t0[idx] = f2bf(k < 16 ? W1f[k * 128 + nn] : 0.f);
    } else if (idx < 4096 + 8192) {
        int r = idx - 4096;
        int nn = r >> 7, k = r & 127;
        w2lt[r] = f2bf(W2l[k * 64 + nn]);
    } else if (idx < 4096 + 8192 + 384) {
        int r = idx - 12288;
        int lm = r >> 7, c = r & 127;
        float s = 0.f;
        for (int o = 0; o < 128; o++) s += b2m[lm * 128 + o] * W1r[(size_t)lm * 16384 + o * 128 + c];
        bvec[r] = s;
    }
}

// w21t[lm][c][i] = bf16( sum_o W2m[lm][i][o] * W1r[lm][o][c] )  -- B-fragment layout [n=c][k=i]
__global__ __launch_bounds__(256) void prep_w21(const float* __restrict__ W2m, const float* __restrict__ W1r,
                                                ushort_t* __restrict__ w21t) {
    int idx = blockIdx.x * 256 + threadIdx.x;  // 49152 total
    int lm = idx >> 14, r = idx & 16383, i = r >> 7, c = r & 127;
    const float* w2row = W2m + (size_t)lm * 16384 + i * 128;   // wave-uniform row
    const float* w1col = W1r + (size_t)lm * 16384 + c;         // coalesced per lane
    float s = 0.f;
#pragma unroll 8
    for (int o = 0; o < 128; o++) s += w2row[o] * w1col[o * 128];
    w21t[(size_t)lm * 16384 + c * 128 + i] = f2bf(s);
}

// A-layout for a 64x128 (or 64x32) bf16 tile: elem(m, k) at ((k>>3)*64 + m)*8 + (k&7)

// ---------------- layer 0: gather fp32 W + MFMA (K=16 padded to 32) ----------------
__global__ __launch_bounds__(256, 4) void gin_mm1_l0(const float* __restrict__ Xf, const ushort_t* __restrict__ W1t,
                                                     const float* __restrict__ b1, const float* __restrict__ eps,
                                                     const int* __restrict__ rp, const int* __restrict__ colv,
                                                     ushort_t* __restrict__ H, float* __restrict__ partial) {
    __shared__ ushort_t Zs[64 * 128];  // 16 KB
    int tid = threadIdx.x, n = blockIdx.x;
    float ev = 1.0f + eps[0];
    int e0 = rp[n], e1 = rp[n + 1], deg = e1 - e0;
    const float4* X = (const float4*)Xf;

    // pipelined gather (slab = 256 float4, 1 per thread)
    float4 sA, sB;
    sA = X[(size_t)n * 256 + tid];
    if (deg > 0) sB = X[(size_t)colv[e0] * 256 + tid];
    float4 a;
    a.x = sA.x * ev; a.y = sA.y * ev; a.z = sA.z * ev; a.w = sA.w * ev;
    int i = 1;
    for (; i + 1 < deg; i += 2) {
        sA = X[(size_t)colv[e0 + i] * 256 + tid];
        a.x += sB.x; a.y += sB.y; a.z += sB.z; a.w += sB.w;
        sB = X[(size_t)colv[e0 + i + 1] * 256 + tid];
        a.x += sA.x; a.y += sA.y; a.z += sA.z; a.w += sA.w;
    }
    if (deg > 0) {
        if (i < deg) {
            sA = X[(size_t)colv[e0 + i] * 256 + tid];
            a.x += sB.x; a.y += sB.y; a.z += sB.z; a.w += sB.w;
            a.x += sA.x; a.y += sA.y; a.z += sA.z; a.w += sA.w;
        } else {
            a.x += sB.x; a.y += sB.y; a.z += sB.z; a.w += sB.w;
        }
    }

    // stage Z into LDS (A-layout), zero k=16..31
    {
        int m = tid >> 2, k0 = (tid & 3) * 4;
        int addr = ((k0 >> 3) * 64 + m) * 8 + (k0 & 7);
        uint2 pv;
        pv.x = f2bf(a.x) | ((unsigned)f2bf(a.y) << 16);
        pv.y = f2bf(a.z) | ((unsigned)f2bf(a.w) << 16);
        *(uint2*)&Zs[addr] = pv;
        *(uint2*)&Zs[1024 + tid * 4] = make_uint2(0u, 0u);
    }
    __syncthreads();

    int w = tid >> 6, lane = tid & 63, lg = lane >> 4, ln = lane & 15;
    floatx4 C[4][2];
#pragma unroll
    for (int mt = 0; mt < 4; mt++) { C[mt][0] = {0.f, 0.f, 0.f, 0.f}; C[mt][1] = {0.f, 0.f, 0.f, 0.f}; }

    {
        short8 B0 = *(const short8*)&W1t[(w * 32 + ln) * 32 + lg * 8];
        short8 B1 = *(const short8*)&W1t[(w * 32 + 16 + ln) * 32 + lg * 8];
#pragma unroll
        for (int mt = 0; mt < 4; mt++) {
            short8 A = *(const short8*)&Zs[(lg * 64 + mt * 16 + ln) * 8];
            C[mt][0] = __builtin_amdgcn_mfma_f32_16x16x32_bf16(A, B0, C[mt][0], 0, 0, 0);
            C[mt][1] = __builtin_amdgcn_mfma_f32_16x16x32_bf16(A, B1, C[mt][1], 0, 0, 0);
        }
    }

    // bias + partial stats + restage + store (epilogue)
    float bsum[2], bsq[2];
    float bv[2] = {b1[w * 32 + ln], b1[w * 32 + 16 + ln]};
#pragma unroll
    for (int nt = 0; nt < 2; nt++) {
        float s = 0.f, s2 = 0.f;
#pragma unroll
        for (int mt = 0; mt < 4; mt++)
#pragma unroll
            for (int r = 0; r < 4; r++) {
                float v = C[mt][nt][r] + bv[nt];
                C[mt][nt][r] = v;
                s += v; s2 += v * v;
            }
        bsum[nt] = s; bsq[nt] = s2;
    }
#pragma unroll
    for (int nt = 0; nt < 2; nt++) {
        bsum[nt] += __shfl_xor(bsum[nt], 16, 64);
        bsum[nt] += __shfl_xor(bsum[nt], 32, 64);
        bsq[nt] += __shfl_xor(bsq[nt], 16, 64);
        bsq[nt] += __shfl_xor(bsq[nt], 32, 64);
    }
    if (lg == 0) {
        int c0 = w * 32 + ln;
        partial[(size_t)n * 256 + c0] = bsum[0];
        partial[(size_t)n * 256 + c0 + 16] = bsum[1];
        partial[(size_t)n * 256 + 128 + c0] = bsq[0];
        partial[(size_t)n * 256 + 128 + c0 + 16] = bsq[1];
    }
    __syncthreads();
#pragma unroll
    for (int nt = 0; nt < 2; nt++) {
        int colc = w * 32 + nt * 16 + ln;
        int base = (colc >> 3) * 512 + (colc & 7);
#pragma unroll
        for (int mt = 0; mt < 4; mt++)
#pragma unroll
            for (int r = 0; r < 4; r++) {
                int row = mt * 16 + lg * 4 + r;
                Zs[base + row * 8] = f2bf(C[mt][nt][r]);
            }
    }
    __syncthreads();
#pragma unroll
    for (int q = 0; q < 4; q++)
        ((uint4*)&H[(size_t)n * 8192])[q * 256 + tid] = ((const uint4*)Zs)[q * 256 + tid];
}

// ---------------- fused layers 1..3 ----------------
// gather relu(bn(Hin)) with pipelined loads, matmul by W21 = W2[l-1]@W1[l],
// bias = b1[c] + (1+eps_l+deg)*bvec[c]; write H + BN partials.
__global__ __launch_bounds__(256, 4) void gin_mm1_fused(const ushort_t* __restrict__ Hin,
                                                        const ushort_t* __restrict__ W21t,
                                                        const float* __restrict__ b1, const float* __restrict__ bvec,
                                                        const float* __restrict__ scshp, const float* __restrict__ epsp,
                                                        const int* __restrict__ rp, const int* __restrict__ colv,
                                                        ushort_t* __restrict__ Hout, float* __restrict__ partial) {
    __shared__ ushort_t Zs[64 * 128];   // 16 KB
    __shared__ float scs_lds[256];      // 1 KB
    int tid = threadIdx.x, n = blockIdx.x;
    scs_lds[tid] = scshp[tid];
    __syncthreads();

    // pack per-thread BN params: q -> k-group kg = q*4 + (tid>>6), cols kg*8+j
    unsigned scp[4][8];
#pragma unroll
    for (int q = 0; q < 4; q++) {
        int cb = (q * 4 + (tid >> 6)) * 8;
#pragma unroll
        for (int j = 0; j < 8; j++)
            scp[q][j] = ((unsigned)f2bf(scs_lds[cb + j])) | ((unsigned)f2bf(scs_lds[128 + cb + j]) << 16);
    }

    float ev = 1.0f + epsp[0];
    int e0 = rp[n], e1 = rp[n + 1], deg = e1 - e0;
    const uint4* X = (const uint4*)Hin;
    float acc[4][8];
    uint4 bufA[4], bufB[4];

    {
        const uint4* p = X + (size_t)n * 1024;
#pragma unroll
        for (int q = 0; q < 4; q++) bufA[q] = p[q * 256 + tid];
    }
    if (deg > 0) {
        const uint4* p = X + (size_t)colv[e0] * 1024;
#pragma unroll
        for (int q = 0; q < 4; q++) bufB[q] = p[q * 256 + tid];
    }

    // self: acc = ev * relu(x*sc + sh)
#pragma unroll
    for (int q = 0; q < 4; q++) {
        float f[8]; unpack8(bufA[q], f);
#pragma unroll
        for (int j = 0; j < 8; j++) {
            float sc = __builtin_bit_cast(float, scp[q][j] << 16);
            float sh = __builtin_bit_cast(float, scp[q][j] & 0xffff0000u);
            acc[q][j] = ev * fmaxf(fmaf(f[j], sc, sh), 0.f);
        }
    }

    auto loadslab = [&](uint4* buf, int node) {
        const uint4* p = X + (size_t)node * 1024;
#pragma unroll
        for (int q = 0; q < 4; q++) buf[q] = p[q * 256 + tid];
    };
    auto addslab = [&](const uint4* buf) {
#pragma unroll
        for (int q = 0; q < 4; q++) {
            float f[8]; unpack8(buf[q], f);
#pragma unroll
            for (int j = 0; j < 8; j++) {
                float sc = __builtin_bit_cast(float, scp[q][j] << 16);
                float sh = __builtin_bit_cast(float, scp[q][j] & 0xffff0000u);
                acc[q][j] += fmaxf(fmaf(f[j], sc, sh), 0.f);
            }
        }
    };

    int i = 1;
    for (; i + 1 < deg; i += 2) {
        loadslab(bufA, colv[e0 + i]);
        addslab(bufB);
        loadslab(bufB, colv[e0 + i + 1]);
        addslab(bufA);
    }
    if (deg > 0) {
        if (i < deg) {
            loadslab(bufA, colv[e0 + i]);
            addslab(bufB);
            addslab(bufA);
        } else {
            addslab(bufB);
        }
    }

#pragma unroll
    for (int q = 0; q < 4; q++) ((uint4*)Zs)[q * 256 + tid] = pack8(acc[q]);
    __syncthreads();

    int w = tid >> 6, lane = tid & 63, lg = lane >> 4, ln = lane & 15;
    floatx4 C[4][2];
#pragma unroll
    for (int mt = 0; mt < 4; mt++) { C[mt][0] = {0.f, 0.f, 0.f, 0.f}; C[mt][1] = {0.f, 0.f, 0.f, 0.f}; }

    for (int kb = 0; kb < 4; kb++) {
        short8 B0 = *(const short8*)&W21t[(w * 32 + ln) * 128 + kb * 32 + lg * 8];
        short8 B1 = *(const short8*)&W21t[(w * 32 + 16 + ln) * 128 + kb * 32 + lg * 8];
#pragma unroll
        for (int mt = 0; mt < 4; mt++) {
            short8 A = *(const short8*)&Zs[((kb * 4 + lg) * 64 + mt * 16 + ln) * 8];
            C[mt][0] = __builtin_amdgcn_mfma_f32_16x16x32_bf16(A, B0, C[mt][0], 0, 0, 0);
            C[mt][1] = __builtin_amdgcn_mfma_f32_16x16x32_bf16(A, B1, C[mt][1], 0, 0, 0);
        }
    }

    // bias (b1 + (ev+deg)*bvec) + partial stats
    float fac = ev + (float)deg;
    int c0 = w * 32 + ln;
    float bv[2] = {b1[c0] + fac * bvec[c0], b1[c0 + 16] + fac * bvec[c0 + 16]};
    float bsum[2], bsq[2];
#pragma unroll
    for (int nt = 0; nt < 2; nt++) {
        float s = 0.f, s2 = 0.f;
#pragma unroll
        for (int mt = 0; mt < 4; mt++)
#pragma unroll
            for (int r = 0; r < 4; r++) {
                float v = C[mt][nt][r] + bv[nt];
                C[mt][nt][r] = v;
                s += v; s2 += v * v;
            }
        bsum[nt] = s; bsq[nt] = s2;
    }
#pragma unroll
    for (int nt = 0; nt < 2; nt++) {
        bsum[nt] += __shfl_xor(bsum[nt], 16, 64);
        bsum[nt] += __shfl_xor(bsum[nt], 32, 64);
        bsq[nt] += __shfl_xor(bsq[nt], 16, 64);
        bsq[nt] += __shfl_xor(bsq[nt], 32, 64);
    }
    if (lg == 0) {
        partial[(size_t)n * 256 + c0] = bsum[0];
        partial[(size_t)n * 256 + c0 + 16] = bsum[1];
        partial[(size_t)n * 256 + 128 + c0] = bsq[0];
        partial[(size_t)n * 256 + 128 + c0 + 16] = bsq[1];
    }
    __syncthreads();
#pragma unroll
    for (int nt = 0; nt < 2; nt++) {
        int colc = w * 32 + nt * 16 + ln;
        int base = (colc >> 3) * 512 + (colc & 7);
#pragma unroll
        for (int mt = 0; mt < 4; mt++)
#pragma unroll
            for (int r = 0; r < 4; r++) {
                int row = mt * 16 + lg * 4 + r;
                Zs[base + row * 8] = f2bf(C[mt][nt][r]);
            }
    }
    __syncthreads();
#pragma unroll
    for (int q = 0; q < 4; q++)
        ((uint4*)&Hout[(size_t)n * 8192])[q * 256 + tid] = ((const uint4*)Zs)[q * 256 + tid];
}

// ---------------- BN stats reduce -> per-feature scale/shift ----------------
__global__ __launch_bounds__(256) void bn_stats(const float* __restrict__ partial, const float* __restrict__ gamma,
                                                const float* __restrict__ beta, float* __restrict__ scsh_out) {
    __shared__ float rs[256], rs2[256];
    int c = blockIdx.x, t = threadIdx.x;
    float s = 0.f, s2 = 0.f;
    for (int b = t; b < 2048; b += 256) {
        s += partial[(size_t)b * 256 + c];
        s2 += partial[(size_t)b * 256 + HIDD + c];
    }
    rs[t] = s; rs2[t] = s2;
    __syncthreads();
    for (int off = 128; off > 0; off >>= 1) {
        if (t < off) { rs[t] += rs[t + off]; rs2[t] += rs2[t + off]; }
        __syncthreads();
    }
    if (t == 0) {
        float mean = rs[0] / (float)ROWS;
        float var = rs2[0] / (float)ROWS - mean * mean;
        float sc = gamma[c] * rsqrtf(var + 1e-5f);
        scsh_out[c] = sc;
        scsh_out[HIDD + c] = beta[c] - mean * sc;
    }
}

// ---------------- final: PE = sum_rows mask * (relu(bn(H3)) @ W2l + b2l) ----------------
__global__ __launch_bounds__(256, 4) void gin_mm2_last(const ushort_t* __restrict__ H, const ushort_t* __restrict__ W2t,
                                                       const float* __restrict__ b2, const float* __restrict__ scsh,
                                                       const float* __restrict__ mask, float* __restrict__ out) {
    __shared__ ushort_t Hs[64 * 128];
    int tid = threadIdx.x, n = blockIdx.x;

#pragma unroll
    for (int q = 0; q < 4; q++) {
        int c = q * 256 + tid;
        uint4 v = ((const uint4*)&H[(size_t)n * 8192])[c];
        float f[8]; unpack8(v, f);
        int cb = (c >> 6) * 8;
#pragma unroll
        for (int j = 0; j < 8; j++) f[j] = fmaxf(fmaf(f[j], scsh[cb + j], scsh[128 + cb + j]), 0.f);
        ((uint4*)Hs)[c] = pack8(f);
    }
    __syncthreads();

    int w = tid >> 6, lane = tid & 63, lg = lane >> 4, ln = lane & 15;
    floatx4 C[4];
#pragma unroll
    for (int mt = 0; mt < 4; mt++) C[mt] = {0.f, 0.f, 0.f, 0.f};

    for (int kb = 0; kb < 4; kb++) {
        short8 B = *(const short8*)&W2t[(w * 16 + ln) * 128 + kb * 32 + lg * 8];
#pragma unroll
        for (int mt = 0; mt < 4; mt++) {
            short8 A = *(const short8*)&Hs[((kb * 4 + lg) * 64 + mt * 16 + ln) * 8];
            C[mt] = __builtin_amdgcn_mfma_f32_16x16x32_bf16(A, B, C[mt], 0, 0, 0);
        }
    }

    int colc = w * 16 + ln;
    float bb = b2[colc];
    float pe = 0.f;
#pragma unroll
    for (int mt = 0; mt < 4; mt++)
#pragma unroll
        for (int r = 0; r < 4; r++) {
            int row = mt * 16 + lg * 4 + r;
            pe += mask[n * 64 + row] * (C[mt][r] + bb);
        }
    pe += __shfl_xor(pe, 16, 64);
    pe += __shfl_xor(pe, 32, 64);
    if (lg == 0) out[(size_t)n * 64 + colc] = pe;
}

// ---------------- host launch ----------------
extern "C" void kernel_launch(void* const* d_in, const int* in_sizes, int n_in, void* d_out, int out_size,
                              void* d_ws, size_t ws_size, hipStream_t stream) {
    const float* W    = (const float*)d_in[0];
    const float* mask = (const float*)d_in[1];
    const int* src    = (const int*)d_in[2];
    const int* dst    = (const int*)d_in[3];
    const float* eps  = (const float*)d_in[4];
    const float* W1f  = (const float*)d_in[5];
    const float* b1f  = (const float*)d_in[6];
    const float* W1r  = (const float*)d_in[7];
    const float* b1r  = (const float*)d_in[8];
    const float* gam  = (const float*)d_in[9];
    const float* bet  = (const float*)d_in[10];
    const float* W2m  = (const float*)d_in[11];
    const float* b2m  = (const float*)d_in[12];
    const float* W2l  = (const float*)d_in[13];
    const float* b2l  = (const float*)d_in[14];
    float* out = (float*)d_out;

    // workspace layout
    ushort_t* Ha   = (ushort_t*)d_ws;          // 16,777,216
    ushort_t* Hb   = Ha + 16777216;            // 16,777,216
    ushort_t* w1t0 = Hb + 16777216;            // 4096
    ushort_t* w2lt = w1t0 + 4096;              // 8192
    ushort_t* w21t = w2lt + 8192;              // 49152
    float* bvec    = (float*)(w21t + 49152);   // 384
    float* partial = bvec + 384;               // 524288
    float* scshL   = partial + 524288;         // 1024 (4 layers x 256)
    int* ideg      = (int*)(scshL + 1024);     // 2048
    int* icur      = ideg + 2048;              // 2048
    int* irp       = icur + 2048;              // 2049
    int* icol      = irp + 2052;               // 16384

    zero_ints<<<16, 256, 0, stream>>>(ideg, 4096);
    count_deg<<<NEDGE / 256, 256, 0, stream>>>(dst, ideg);
    scan_deg<<<1, 256, 0, stream>>>(ideg, irp);
    fill_csr<<<NEDGE / 256, 256, 0, stream>>>(src, dst, irp, icur, icol);
    prep_small<<<50, 256, 0, stream>>>(W1f, W2l, b2m, W1r, w1t0, w2lt, bvec);
    prep_w21<<<192, 256, 0, stream>>>(W2m, W1r, w21t);

    // layer 0
    gin_mm1_l0<<<N_SUM, 256, 0, stream>>>(W, w1t0, b1f, eps, irp, icol, Ha, partial);
    bn_stats<<<HIDD, 256, 0, stream>>>(partial, gam, bet, scshL);
    // layer 1
    gin_mm1_fused<<<N_SUM, 256, 0, stream>>>(Ha, w21t, b1r, bvec, scshL, eps + 1, irp, icol, Hb, partial);
    bn_stats<<<HIDD, 256, 0, stream>>>(partial, gam + 128, bet + 128, scshL + 256);
    // layer 2
    gin_mm1_fused<<<N_SUM, 256, 0, stream>>>(Hb, w21t + 16384, b1r + 128, bvec + 128, scshL + 256, eps + 2,
                                             irp, icol, Ha, partial);
    bn_stats<<<HIDD, 256, 0, stream>>>(partial, gam + 256, bet + 256, scshL + 512);
    // layer 3
    gin_mm1_fused<<<N_SUM, 256, 0, stream>>>(Ha, w21t + 32768, b1r + 256, bvec + 256, scshL + 512, eps + 3,
                                             irp, icol, Hb, partial);
    bn_stats<<<HIDD, 256, 0, stream>>>(partial, gam + 384, bet + 384, scshL + 768);
    // final
    gin_mm2_last<<<N_SUM, 256, 0, stream>>>(Hb, w2lt, b2l, scshL + 768, mask, out);
}

// Round 5
// 309.157 us; speedup vs baseline: 1.6549x; 1.6549x over previous
//
#include <hip/hip_runtime.h>

#define N_SUM 2048
#define HIDD 128
#define NEDGE 16384
#define ROWS (N_SUM * 64)

typedef short short8 __attribute__((ext_vector_type(8)));
typedef float floatx4 __attribute__((ext_vector_type(4)));
typedef unsigned int uint4n __attribute__((ext_vector_type(4)));  // native vector for nontemporal builtins
typedef unsigned short ushort_t;

__device__ __forceinline__ ushort_t f2bf(float f) {
    unsigned u = __builtin_bit_cast(unsigned, f);
    u += 0x7fffu + ((u >> 16) & 1u);   // RNE
    return (ushort_t)(u >> 16);
}
__device__ __forceinline__ float bf2f(ushort_t h) {
    return __builtin_bit_cast(float, (unsigned)h << 16);
}
__device__ __forceinline__ void unpack8(uint4 v, float* f) {
    f[0] = bf2f(v.x & 0xffff); f[1] = bf2f(v.x >> 16);
    f[2] = bf2f(v.y & 0xffff); f[3] = bf2f(v.y >> 16);
    f[4] = bf2f(v.z & 0xffff); f[5] = bf2f(v.z >> 16);
    f[6] = bf2f(v.w & 0xffff); f[7] = bf2f(v.w >> 16);
}
__device__ __forceinline__ uint4 pack8(const float* f) {
    uint4 v;
    v.x = f2bf(f[0]) | ((unsigned)f2bf(f[1]) << 16);
    v.y = f2bf(f[2]) | ((unsigned)f2bf(f[3]) << 16);
    v.z = f2bf(f[4]) | ((unsigned)f2bf(f[5]) << 16);
    v.w = f2bf(f[6]) | ((unsigned)f2bf(f[7]) << 16);
    return v;
}
__device__ __forceinline__ void nt_store16(const void* src, void* dst) {
    __builtin_nontemporal_store(*(const uint4n*)src, (uint4n*)dst);
}

// ---------------- CSR build ----------------
__global__ __launch_bounds__(256) void zero_ints(int* p, int n) {
    int i = blockIdx.x * 256 + threadIdx.x;
    if (i < n) p[i] = 0;
}

__global__ __launch_bounds__(256) void count_deg(const int* __restrict__ dst, int* __restrict__ deg) {
    int e = blockIdx.x * 256 + threadIdx.x;
    if (e < NEDGE) atomicAdd(&deg[dst[e]], 1);
}

__global__ __launch_bounds__(256) void scan_deg(const int* __restrict__ deg, int* __restrict__ row_ptr) {
    __shared__ int csum[256];
    int t = threadIdx.x;
    int loc[8];
    int s = 0;
#pragma unroll
    for (int q = 0; q < 8; q++) { loc[q] = s; s += deg[t * 8 + q]; }
    csum[t] = s;
    __syncthreads();
    for (int off = 1; off < 256; off <<= 1) {
        int v = (t >= off) ? csum[t - off] : 0;
        __syncthreads();
        csum[t] += v;
        __syncthreads();
    }
    int base = (t == 0) ? 0 : csum[t - 1];
#pragma unroll
    for (int q = 0; q < 8; q++) row_ptr[t * 8 + q] = base + loc[q];
    if (t == 255) row_ptr[2048] = csum[255];
}

__global__ __launch_bounds__(256) void fill_csr(const int* __restrict__ src, const int* __restrict__ dst,
                                                const int* __restrict__ row_ptr, int* __restrict__ cursor,
                                                int* __restrict__ col) {
    int e = blockIdx.x * 256 + threadIdx.x;
    if (e < NEDGE) {
        int d = dst[e];
        int pos = atomicAdd(&cursor[d], 1);
        col[row_ptr[d] + pos] = src[e];
    }
}

// ---------------- weight prep ----------------
__global__ __launch_bounds__(256) void prep_small(const float* __restrict__ W1f, const float* __restrict__ W2l,
                                                  const float* __restrict__ b2m, const float* __restrict__ W1r,
                                                  ushort_t* __restrict__ w1t0, ushort_t* __restrict__ w2lt,
                                                  float* __restrict__ bvec) {
    int idx = blockIdx.x * 256 + threadIdx.x;
    if (idx < 4096) {
        int nn = idx >> 5, k = idx & 31;
        w1t0[idx] = f2bf(k < 16 ? W1f[k * 128 + nn] : 0.f);
    } else if (idx < 4096 + 8192) {
        int r = idx - 4096;
        int nn = r >> 7, k = r & 127;
        w2lt[r] = f2bf(W2l[k * 64 + nn]);
    } else if (idx < 4096 + 8192 + 384) {
        int r = idx - 12288;
        int lm = r >> 7, c = r & 127;
        float s = 0.f;
        for (int o = 0; o < 128; o++) s += b2m[lm * 128 + o] * W1r[(size_t)lm * 16384 + o * 128 + c];
        bvec[r] = s;
    }
}

// w21t[lm][c][i] = bf16( sum_o W2m[lm][i][o] * W1r[lm][o][c] )  -- B-fragment layout [n=c][k=i]
__global__ __launch_bounds__(256) void prep_w21(const float* __restrict__ W2m, const float* __restrict__ W1r,
                                                ushort_t* __restrict__ w21t) {
    int idx = blockIdx.x * 256 + threadIdx.x;  // 49152 total
    int lm = idx >> 14, r = idx & 16383, i = r >> 7, c = r & 127;
    const float* w2row = W2m + (size_t)lm * 16384 + i * 128;
    const float* w1col = W1r + (size_t)lm * 16384 + c;
    float s = 0.f;
#pragma unroll 8
    for (int o = 0; o < 128; o++) s += w2row[o] * w1col[o * 128];
    w21t[(size_t)lm * 16384 + c * 128 + i] = f2bf(s);
}

// A-layout for a 64x128 (or 64x32) bf16 tile: elem(m, k) at ((k>>3)*64 + m)*8 + (k&7)

// ---------------- layer 0: gather fp32 W + MFMA (K=16 padded to 32) ----------------
__global__ __launch_bounds__(256, 4) void gin_mm1_l0(const float* __restrict__ Xf, const ushort_t* __restrict__ W1t,
                                                     const float* __restrict__ b1, const float* __restrict__ eps,
                                                     const int* __restrict__ rp, const int* __restrict__ colv,
                                                     ushort_t* __restrict__ H, float* __restrict__ partial) {
    __shared__ ushort_t Zs[64 * 128];  // 16 KB
    int tid = threadIdx.x, n = blockIdx.x;
    float ev = 1.0f + eps[0];
    int e0 = rp[n], e1 = rp[n + 1], deg = e1 - e0;
    const float4* X = (const float4*)Xf;

    float4 sA, sB;
    sA = X[(size_t)n * 256 + tid];
    if (deg > 0) sB = X[(size_t)colv[e0] * 256 + tid];
    float4 a;
    a.x = sA.x * ev; a.y = sA.y * ev; a.z = sA.z * ev; a.w = sA.w * ev;
    int i = 1;
    for (; i + 1 < deg; i += 2) {
        sA = X[(size_t)colv[e0 + i] * 256 + tid];
        a.x += sB.x; a.y += sB.y; a.z += sB.z; a.w += sB.w;
        sB = X[(size_t)colv[e0 + i + 1] * 256 + tid];
        a.x += sA.x; a.y += sA.y; a.z += sA.z; a.w += sA.w;
    }
    if (deg > 0) {
        if (i < deg) {
            sA = X[(size_t)colv[e0 + i] * 256 + tid];
            a.x += sB.x; a.y += sB.y; a.z += sB.z; a.w += sB.w;
            a.x += sA.x; a.y += sA.y; a.z += sA.z; a.w += sA.w;
        } else {
            a.x += sB.x; a.y += sB.y; a.z += sB.z; a.w += sB.w;
        }
    }

    {
        int m = tid >> 2, k0 = (tid & 3) * 4;
        int addr = ((k0 >> 3) * 64 + m) * 8 + (k0 & 7);
        uint2 pv;
        pv.x = f2bf(a.x) | ((unsigned)f2bf(a.y) << 16);
        pv.y = f2bf(a.z) | ((unsigned)f2bf(a.w) << 16);
        *(uint2*)&Zs[addr] = pv;
        *(uint2*)&Zs[1024 + tid * 4] = make_uint2(0u, 0u);
    }
    __syncthreads();

    int w = tid >> 6, lane = tid & 63, lg = lane >> 4, ln = lane & 15;
    floatx4 C[4][2];
#pragma unroll
    for (int mt = 0; mt < 4; mt++) { C[mt][0] = {0.f, 0.f, 0.f, 0.f}; C[mt][1] = {0.f, 0.f, 0.f, 0.f}; }

    {
        short8 B0 = *(const short8*)&W1t[(w * 32 + ln) * 32 + lg * 8];
        short8 B1 = *(const short8*)&W1t[(w * 32 + 16 + ln) * 32 + lg * 8];
#pragma unroll
        for (int mt = 0; mt < 4; mt++) {
            short8 A = *(const short8*)&Zs[(lg * 64 + mt * 16 + ln) * 8];
            C[mt][0] = __builtin_amdgcn_mfma_f32_16x16x32_bf16(A, B0, C[mt][0], 0, 0, 0);
            C[mt][1] = __builtin_amdgcn_mfma_f32_16x16x32_bf16(A, B1, C[mt][1], 0, 0, 0);
        }
    }

    float bsum[2], bsq[2];
    float bv[2] = {b1[w * 32 + ln], b1[w * 32 + 16 + ln]};
#pragma unroll
    for (int nt = 0; nt < 2; nt++) {
        float s = 0.f, s2 = 0.f;
#pragma unroll
        for (int mt = 0; mt < 4; mt++)
#pragma unroll
            for (int r = 0; r < 4; r++) {
                float v = C[mt][nt][r] + bv[nt];
                C[mt][nt][r] = v;
                s += v; s2 += v * v;
            }
        bsum[nt] = s; bsq[nt] = s2;
    }
#pragma unroll
    for (int nt = 0; nt < 2; nt++) {
        bsum[nt] += __shfl_xor(bsum[nt], 16, 64);
        bsum[nt] += __shfl_xor(bsum[nt], 32, 64);
        bsq[nt] += __shfl_xor(bsq[nt], 16, 64);
        bsq[nt] += __shfl_xor(bsq[nt], 32, 64);
    }
    if (lg == 0) {
        int c0 = w * 32 + ln;
        __builtin_nontemporal_store(bsum[0], &partial[(size_t)n * 256 + c0]);
        __builtin_nontemporal_store(bsum[1], &partial[(size_t)n * 256 + c0 + 16]);
        __builtin_nontemporal_store(bsq[0], &partial[(size_t)n * 256 + 128 + c0]);
        __builtin_nontemporal_store(bsq[1], &partial[(size_t)n * 256 + 128 + c0 + 16]);
    }
    __syncthreads();
#pragma unroll
    for (int nt = 0; nt < 2; nt++) {
        int colc = w * 32 + nt * 16 + ln;
        int base = (colc >> 3) * 512 + (colc & 7);
#pragma unroll
        for (int mt = 0; mt < 4; mt++)
#pragma unroll
            for (int r = 0; r < 4; r++) {
                int row = mt * 16 + lg * 4 + r;
                Zs[base + row * 8] = f2bf(C[mt][nt][r]);
            }
    }
    __syncthreads();
#pragma unroll
    for (int q = 0; q < 4; q++)
        nt_store16(&((const uint4*)Zs)[q * 256 + tid], &((uint4*)&H[(size_t)n * 8192])[q * 256 + tid]);
}

// ---------------- fused layers 1..3 (512 threads, low register pressure) ----------------
// gather relu(bn(Hin)) pipelined, matmul by W21 = W2[l-1]@W1[l],
// bias = b1[c] + (1+eps_l+deg)*bvec[c]; write Hout + BN partials.
__global__ __launch_bounds__(512, 4) void gin_mm1_fused(const ushort_t* __restrict__ Hin,
                                                        const ushort_t* __restrict__ W21t,
                                                        const float* __restrict__ b1, const float* __restrict__ bvec,
                                                        const float* __restrict__ scshp, const float* __restrict__ epsp,
                                                        const int* __restrict__ rp, const int* __restrict__ colv,
                                                        ushort_t* __restrict__ Hout, float* __restrict__ partial) {
    __shared__ ushort_t Zs[64 * 128];   // 16 KB
    __shared__ float scs_lds[256];      // 1 KB
    int tid = threadIdx.x, n = blockIdx.x;
    if (tid < 256) scs_lds[tid] = scshp[tid];
    __syncthreads();

    // per-thread BN params for its 2 chunks: chunk q at c = q*512+tid, k-group kg=c>>6, cols kg*8+j
    unsigned scp[2][8];
#pragma unroll
    for (int q = 0; q < 2; q++) {
        int cb = ((q * 512 + tid) >> 6) * 8;
#pragma unroll
        for (int j = 0; j < 8; j++)
            scp[q][j] = ((unsigned)f2bf(scs_lds[cb + j])) | ((unsigned)f2bf(scs_lds[128 + cb + j]) << 16);
    }

    float ev = 1.0f + epsp[0];
    int e0 = rp[n], e1 = rp[n + 1], deg = e1 - e0;
    const uint4* X = (const uint4*)Hin;
    float acc[2][8];
    uint4 bufA[2], bufB[2];

    {
        const uint4* p = X + (size_t)n * 1024;
#pragma unroll
        for (int q = 0; q < 2; q++) bufA[q] = p[q * 512 + tid];
    }
    if (deg > 0) {
        const uint4* p = X + (size_t)colv[e0] * 1024;
#pragma unroll
        for (int q = 0; q < 2; q++) bufB[q] = p[q * 512 + tid];
    }

    // self: acc = ev * relu(x*sc + sh)
#pragma unroll
    for (int q = 0; q < 2; q++) {
        float f[8]; unpack8(bufA[q], f);
#pragma unroll
        for (int j = 0; j < 8; j++) {
            float sc = __builtin_bit_cast(float, scp[q][j] << 16);
            float sh = __builtin_bit_cast(float, scp[q][j] & 0xffff0000u);
            acc[q][j] = ev * fmaxf(fmaf(f[j], sc, sh), 0.f);
        }
    }

    auto loadslab = [&](uint4* buf, int node) {
        const uint4* p = X + (size_t)node * 1024;
#pragma unroll
        for (int q = 0; q < 2; q++) buf[q] = p[q * 512 + tid];
    };
    auto addslab = [&](const uint4* buf) {
#pragma unroll
        for (int q = 0; q < 2; q++) {
            float f[8]; unpack8(buf[q], f);
#pragma unroll
            for (int j = 0; j < 8; j++) {
                float sc = __builtin_bit_cast(float, scp[q][j] << 16);
                float sh = __builtin_bit_cast(float, scp[q][j] & 0xffff0000u);
                acc[q][j] += fmaxf(fmaf(f[j], sc, sh), 0.f);
            }
        }
    };

    int i = 1;
    for (; i + 1 < deg; i += 2) {
        loadslab(bufA, colv[e0 + i]);
        addslab(bufB);
        loadslab(bufB, colv[e0 + i + 1]);
        addslab(bufA);
    }
    if (deg > 0) {
        if (i < deg) {
            loadslab(bufA, colv[e0 + i]);
            addslab(bufB);
            addslab(bufA);
        } else {
            addslab(bufB);
        }
    }

#pragma unroll
    for (int q = 0; q < 2; q++) ((uint4*)Zs)[q * 512 + tid] = pack8(acc[q]);
    __syncthreads();

    // MFMA: 8 waves, each owns 16 output cols, all 64 rows (4 M-tiles)
    int w = tid >> 6, lane = tid & 63, lg = lane >> 4, ln = lane & 15;
    floatx4 C[4];
#pragma unroll
    for (int mt = 0; mt < 4; mt++) C[mt] = {0.f, 0.f, 0.f, 0.f};

    for (int kb = 0; kb < 4; kb++) {
        short8 B = *(const short8*)&W21t[(w * 16 + ln) * 128 + kb * 32 + lg * 8];
#pragma unroll
        for (int mt = 0; mt < 4; mt++) {
            short8 A = *(const short8*)&Zs[((kb * 4 + lg) * 64 + mt * 16 + ln) * 8];
            C[mt] = __builtin_amdgcn_mfma_f32_16x16x32_bf16(A, B, C[mt], 0, 0, 0);
        }
    }

    // bias (b1 + (ev+deg)*bvec) + partial stats
    float fac = ev + (float)deg;
    int c0 = w * 16 + ln;
    float bv = b1[c0] + fac * bvec[c0];
    float s = 0.f, s2 = 0.f;
#pragma unroll
    for (int mt = 0; mt < 4; mt++)
#pragma unroll
        for (int r = 0; r < 4; r++) {
            float v = C[mt][r] + bv;
            C[mt][r] = v;
            s += v; s2 += v * v;
        }
    s += __shfl_xor(s, 16, 64);
    s += __shfl_xor(s, 32, 64);
    s2 += __shfl_xor(s2, 16, 64);
    s2 += __shfl_xor(s2, 32, 64);
    if (lg == 0) {
        __builtin_nontemporal_store(s, &partial[(size_t)n * 256 + c0]);
        __builtin_nontemporal_store(s2, &partial[(size_t)n * 256 + 128 + c0]);
    }

    // C-layout -> A-layout bf16 via LDS, then coalesced nontemporal store
    __syncthreads();
    {
        int base = (c0 >> 3) * 512 + (c0 & 7);
#pragma unroll
        for (int mt = 0; mt < 4; mt++)
#pragma unroll
            for (int r = 0; r < 4; r++) {
                int row = mt * 16 + lg * 4 + r;
                Zs[base + row * 8] = f2bf(C[mt][r]);
            }
    }
    __syncthreads();
#pragma unroll
    for (int q = 0; q < 2; q++)
        nt_store16(&((const uint4*)Zs)[q * 512 + tid], &((uint4*)&Hout[(size_t)n * 8192])[q * 512 + tid]);
}

// ---------------- BN stats reduce -> per-feature scale/shift ----------------
__global__ __launch_bounds__(256) void bn_stats(const float* __restrict__ partial, const float* __restrict__ gamma,
                                                const float* __restrict__ beta, float* __restrict__ scsh_out) {
    __shared__ float rs[256], rs2[256];
    int c = blockIdx.x, t = threadIdx.x;
    float s = 0.f, s2 = 0.f;
    for (int b = t; b < 2048; b += 256) {
        s += partial[(size_t)b * 256 + c];
        s2 += partial[(size_t)b * 256 + HIDD + c];
    }
    rs[t] = s; rs2[t] = s2;
    __syncthreads();
    for (int off = 128; off > 0; off >>= 1) {
        if (t < off) { rs[t] += rs[t + off]; rs2[t] += rs2[t + off]; }
        __syncthreads();
    }
    if (t == 0) {
        float mean = rs[0] / (float)ROWS;
        float var = rs2[0] / (float)ROWS - mean * mean;
        float sc = gamma[c] * rsqrtf(var + 1e-5f);
        scsh_out[c] = sc;
        scsh_out[HIDD + c] = beta[c] - mean * sc;
    }
}

// ---------------- final: PE = sum_rows mask * (relu(bn(H3)) @ W2l + b2l) ----------------
__global__ __launch_bounds__(256, 4) void gin_mm2_last(const ushort_t* __restrict__ H, const ushort_t* __restrict__ W2t,
                                                       const float* __restrict__ b2, const float* __restrict__ scsh,
                                                       const float* __restrict__ mask, float* __restrict__ out) {
    __shared__ ushort_t Hs[64 * 128];
    int tid = threadIdx.x, n = blockIdx.x;

#pragma unroll
    for (int q = 0; q < 4; q++) {
        int c = q * 256 + tid;
        uint4 v = ((const uint4*)&H[(size_t)n * 8192])[c];
        float f[8]; unpack8(v, f);
        int cb = (c >> 6) * 8;
#pragma unroll
        for (int j = 0; j < 8; j++) f[j] = fmaxf(fmaf(f[j], scsh[cb + j], scsh[128 + cb + j]), 0.f);
        ((uint4*)Hs)[c] = pack8(f);
    }
    __syncthreads();

    int w = tid >> 6, lane = tid & 63, lg = lane >> 4, ln = lane & 15;
    floatx4 C[4];
#pragma unroll
    for (int mt = 0; mt < 4; mt++) C[mt] = {0.f, 0.f, 0.f, 0.f};

    for (int kb = 0; kb < 4; kb++) {
        short8 B = *(const short8*)&W2t[(w * 16 + ln) * 128 + kb * 32 + lg * 8];
#pragma unroll
        for (int mt = 0; mt < 4; mt++) {
            short8 A = *(const short8*)&Hs[((kb * 4 + lg) * 64 + mt * 16 + ln) * 8];
            C[mt] = __builtin_amdgcn_mfma_f32_16x16x32_bf16(A, B, C[mt], 0, 0, 0);
        }
    }

    int colc = w * 16 + ln;
    float bb = b2[colc];
    float pe = 0.f;
#pragma unroll
    for (int mt = 0; mt < 4; mt++)
#pragma unroll
        for (int r = 0; r < 4; r++) {
            int row = mt * 16 + lg * 4 + r;
            pe += mask[n * 64 + row] * (C[mt][r] + bb);
        }
    pe += __shfl_xor(pe, 16, 64);
    pe += __shfl_xor(pe, 32, 64);
    if (lg == 0) out[(size_t)n * 64 + colc] = pe;
}

// ---------------- host launch ----------------
extern "C" void kernel_launch(void* const* d_in, const int* in_sizes, int n_in, void* d_out, int out_size,
                              void* d_ws, size_t ws_size, hipStream_t stream) {
    const float* W    = (const float*)d_in[0];
    const float* mask = (const float*)d_in[1];
    const int* src    = (const int*)d_in[2];
    const int* dst    = (const int*)d_in[3];
    const float* eps  = (const float*)d_in[4];
    const float* W1f  = (const float*)d_in[5];
    const float* b1f  = (const float*)d_in[6];
    const float* W1r  = (const float*)d_in[7];
    const float* b1r  = (const float*)d_in[8];
    const float* gam  = (const float*)d_in[9];
    const float* bet  = (const float*)d_in[10];
    const float* W2m  = (const float*)d_in[11];
    const float* b2m  = (const float*)d_in[12];
    const float* W2l  = (const float*)d_in[13];
    const float* b2l  = (const float*)d_in[14];
    float* out = (float*)d_out;

    // workspace layout
    ushort_t* Ha   = (ushort_t*)d_ws;          // 16,777,216
    ushort_t* Hb   = Ha + 16777216;            // 16,777,216
    ushort_t* w1t0 = Hb + 16777216;            // 4096
    ushort_t* w2lt = w1t0 + 4096;              // 8192
    ushort_t* w21t = w2lt + 8192;              // 49152
    float* bvec    = (float*)(w21t + 49152);   // 384
    float* partial = bvec + 384;               // 524288
    float* scshL   = partial + 524288;         // 1024 (4 layers x 256)
    int* ideg      = (int*)(scshL + 1024);     // 2048
    int* icur      = ideg + 2048;              // 2048
    int* irp       = icur + 2048;              // 2049
    int* icol      = irp + 2052;               // 16384

    zero_ints<<<16, 256, 0, stream>>>(ideg, 4096);
    count_deg<<<NEDGE / 256, 256, 0, stream>>>(dst, ideg);
    scan_deg<<<1, 256, 0, stream>>>(ideg, irp);
    fill_csr<<<NEDGE / 256, 256, 0, stream>>>(src, dst, irp, icur, icol);
    prep_small<<<50, 256, 0, stream>>>(W1f, W2l, b2m, W1r, w1t0, w2lt, bvec);
    prep_w21<<<192, 256, 0, stream>>>(W2m, W1r, w21t);

    // layer 0
    gin_mm1_l0<<<N_SUM, 256, 0, stream>>>(W, w1t0, b1f, eps, irp, icol, Ha, partial);
    bn_stats<<<HIDD, 256, 0, stream>>>(partial, gam, bet, scshL);
    // layer 1
    gin_mm1_fused<<<N_SUM, 512, 0, stream>>>(Ha, w21t, b1r, bvec, scshL, eps + 1, irp, icol, Hb, partial);
    bn_stats<<<HIDD, 256, 0, stream>>>(partial, gam + 128, bet + 128, scshL + 256);
    // layer 2
    gin_mm1_fused<<<N_SUM, 512, 0, stream>>>(Hb, w21t + 16384, b1r + 128, bvec + 128, scshL + 256, eps + 2,
                                             irp, icol, Ha, partial);
    bn_stats<<<HIDD, 256, 0, stream>>>(partial, gam + 256, bet + 256, scshL + 512);
    // layer 3
    gin_mm1_fused<<<N_SUM, 512, 0, stream>>>(Ha, w21t + 32768, b1r + 256, bvec + 256, scshL + 512, eps + 3,
                                             irp, icol, Hb, partial);
    bn_stats<<<HIDD, 256, 0, stream>>>(partial, gam + 384, bet + 384, scshL + 768);
    // final
    gin_mm2_last<<<N_SUM, 256, 0, stream>>>(Hb, w2lt, b2l, scshL + 768, mask, out);
}